// Round 21
// baseline (140.290 us; speedup 1.0000x reference)
//
#include <hip/hip_runtime.h>

#define SK 8192
#define SQ 8192
#define DD 128
#define ZSPLIT 16

typedef __attribute__((ext_vector_type(8))) short short8;
typedef __attribute__((ext_vector_type(4))) float f32x4;
typedef __attribute__((ext_vector_type(4))) unsigned uint4v;
typedef unsigned short ushort_t;

// round-to-nearest-even f32 -> bf16
__device__ __forceinline__ unsigned short f2bf(float x){
  unsigned int u = __float_as_uint(x);
  u += 0x7FFFu + ((u >> 16) & 1u);
  return (unsigned short)(u >> 16);
}

// async global->LDS DMA, 16B/lane. LDS dest = uniform base + lane*16.
__device__ __forceinline__ void gld16(const void* g, void* l){
  __builtin_amdgcn_global_load_lds(
      (const __attribute__((address_space(1))) unsigned int*)g,
      (__attribute__((address_space(3))) unsigned int*)l, 16, 0, 0);
}

// ---------------------------------------------------------------------------
// STREAM LAYOUTS (fragment-record form; all reads are coalesced 1KB records)
// K/Q stream: per 64-row tile, 16 records of 1KB; rec = rg*4 + kk.
//   Lane l, byte pair j: element M[tile*64 + rg*16 + (l&15)][kk*32 + (l>>4)*8 + j]
// V stream: per 64-q tile, 16 records; rec = qc*8 + dvb. Lane l:
//   element V^T[dvb*16 + (l&15)][qc*32 + (l>>4)*8 + j]  (V^T pre-scaled 1/Z)
// ---------------------------------------------------------------------------

// prep_kq: cast K (pre-scaled by log2(e)/sqrt(128)) and Q to bf16 streams.
__global__ __launch_bounds__(256) void prep_kq(const float* __restrict__ Kp,
                                               const float* __restrict__ Qp,
                                               ushort_t* __restrict__ kst,
                                               ushort_t* __restrict__ qst){
  int g = blockIdx.x*256 + threadIdx.x;
  int arr = g >> 17;
  int s   = g & 131071;
  int row = s >> 4;
  int c16 = s & 15;            // 8-elem slot: d = c16*8..c16*8+7
  const float* src = (arr ? Qp : Kp) + row*DD + c16*8;
  const float scale = arr ? 1.0f : 0.12751743f;   // log2(e)/sqrt(128)
  float4 f0 = ((const float4*)src)[0];
  float4 f1 = ((const float4*)src)[1];
  unsigned int wv[4];
  wv[0] = (unsigned)f2bf(f0.x*scale) | ((unsigned)f2bf(f0.y*scale) << 16);
  wv[1] = (unsigned)f2bf(f0.z*scale) | ((unsigned)f2bf(f0.w*scale) << 16);
  wv[2] = (unsigned)f2bf(f1.x*scale) | ((unsigned)f2bf(f1.y*scale) << 16);
  wv[3] = (unsigned)f2bf(f1.z*scale) | ((unsigned)f2bf(f1.w*scale) << 16);
  ushort_t* base = arr ? qst : kst;
  int tile = row >> 6, rg = (row >> 4) & 3, r15 = row & 15;
  int kk = c16 >> 2, g4 = c16 & 3;
  char* dst = (char*)base + (size_t)tile*16384 + (rg*4 + kk)*1024 + (g4*16 + r15)*16;
  ((uint4*)dst)[0] = make_uint4(wv[0],wv[1],wv[2],wv[3]);
}

// ---------------------------------------------------------------------------
// kz: per-column stats, 128-q stripes (Q in LDS, 32KB) x 16 k-splits.
// Each K record now feeds 8 MFMAs (vs 4) -> K L2 traffic halves to 128MB.
// Grid 1024 = 64 q-stripes x 16 kspl; 4 blocks/CU, 16 waves/CU (VGPR~100).
// Barrier-free main loop + 1-deep K register prefetch (r17-proven).
// ---------------------------------------------------------------------------
__global__ __launch_bounds__(256, 4) void kz(const ushort_t* __restrict__ kst,
                                             const ushort_t* __restrict__ qst,
                                             float* __restrict__ zpart){
  __shared__ __align__(16) char smem[34816];   // Q 32KB | zred 2KB
  int wg = blockIdx.x;            // 1024
  int qs2  = wg >> 4;             // 0..63 (128-q stripe = 2 tiles)
  int kspl = wg & 15;             // 0..15 (8 k-tiles each)
  int t = threadIdx.x, lane = t & 63, w = t >> 6;   // w in 0..3

  // stage the 2 Q tile images (32KB) once
  { const char* qg = (const char*)qst + (size_t)(qs2*2)*16384;
    #pragma unroll
    for (int i=0;i<8;i++)
      gld16(qg + (t + i*256)*16, smem + (t + i*256)*16);
  }
  __syncthreads();

  const char* kbase = (const char*)kst + (size_t)(kspl*8)*16384 + ((w*4)<<10) + lane*16;
  short8 ak[4];
  #pragma unroll
  for (int kk=0;kk<4;kk++)
    ak[kk] = *(const short8*)(kbase + (kk<<10));

  float zac[8];
  #pragma unroll
  for (int i=0;i<8;i++) zac[i] = 0.f;

  for (int it=0; it<8; ++it){
    int nit = (it+1 < 8) ? it+1 : 7;
    short8 nk[4];
    #pragma unroll
    for (int kk=0;kk<4;kk++)
      nk[kk] = *(const short8*)(kbase + (size_t)nit*16384 + (kk<<10));
    f32x4 s[8];
    #pragma unroll
    for (int i=0;i<8;i++) s[i] = (f32x4){0.f,0.f,0.f,0.f};
    #pragma unroll
    for (int kk=0; kk<4; ++kk){
      #pragma unroll
      for (int qg_=0; qg_<8; ++qg_){
        short8 qf = *(const short8*)(smem + ((qg_*4+kk)<<10) + lane*16);
        s[qg_] = __builtin_amdgcn_mfma_f32_16x16x32_bf16(ak[kk], qf, s[qg_], 0, 0, 0);
      }
    }
    #pragma unroll
    for (int qg_=0; qg_<8; ++qg_)
      #pragma unroll
      for (int j=0;j<4;j++)
        zac[qg_] += __builtin_exp2f(s[qg_][j]);
    #pragma unroll
    for (int kk=0;kk<4;kk++) ak[kk] = nk[kk];
  }
  // reduce across g4 (k-subrows) within wave, then across the 4 waves
  #pragma unroll
  for (int qg_=0; qg_<8; ++qg_){
    zac[qg_] += __shfl_xor(zac[qg_],16);
    zac[qg_] += __shfl_xor(zac[qg_],32);
  }
  float* zred = (float*)(smem + 32768);   // [w][128 q]
  if (lane < 16){
    #pragma unroll
    for (int qg_=0; qg_<8; ++qg_)
      zred[w*128 + qg_*16 + lane] = zac[qg_];
  }
  __syncthreads();
  if (t < 128){
    float z = zred[t] + zred[128+t] + zred[256+t] + zred[384+t];
    zpart[(size_t)kspl*SQ + qs2*128 + t] = z;
  }
}

// ---------------------------------------------------------------------------
// prep_v: runs AFTER kz. Vt[q,:] = V[q,:] / Z_q -> V stream records.
// Grid 256 = 128 tiles x 2 q-halves (r20 — passing). ZSPLIT now 16.
// ---------------------------------------------------------------------------
__global__ __launch_bounds__(256) void prep_v(const float* __restrict__ Vp,
                                              const float* __restrict__ zpart,
                                              ushort_t* __restrict__ vst){
  __shared__ ushort_t vl[32][132];
  int tile = blockIdx.x >> 1;     // 0..127
  int qc   = blockIdx.x & 1;      // q-half
  int t = threadIdx.x;
  int qr = t >> 3;                // 0..31 local q row
  int dvb16 = (t & 7)*16;         // dv chunk of 16
  int q = tile*64 + qc*32 + qr;
  float z = 0.f;
  #pragma unroll
  for (int s=0;s<ZSPLIT;s++) z += zpart[(size_t)s*SQ + q];
  float vinv = 1.0f / z;
  const float* src = Vp + (size_t)q*DD + dvb16;
  #pragma unroll
  for (int j=0;j<4;j++){
    float4 f = ((const float4*)src)[j];
    vl[qr][dvb16 + j*4 + 0] = f2bf(f.x*vinv);
    vl[qr][dvb16 + j*4 + 1] = f2bf(f.y*vinv);
    vl[qr][dvb16 + j*4 + 2] = f2bf(f.z*vinv);
    vl[qr][dvb16 + j*4 + 3] = f2bf(f.w*vinv);
  }
  __syncthreads();
  char* obase = (char*)vst + (size_t)tile*16384;
  #pragma unroll
  for (int s2=0;s2<2;s2++){
    int sid = t*2 + s2;                 // 0..511 = rec_local*64 + lane
    int recl = sid >> 6, lr = sid & 63;
    int dv = recl*16 + (lr & 15);       // recl = dvb (0..7)
    int qb = (lr >> 4)*8;               // local q base within half
    unsigned int wv[4];
    #pragma unroll
    for (int p=0;p<4;p++){
      unsigned lo = vl[qb + p*2 + 0][dv];
      unsigned hi = vl[qb + p*2 + 1][dv];
      wv[p] = lo | (hi << 16);
    }
    ((uint4*)(obase + (qc*8 + recl)*1024 + lr*16))[0] = make_uint4(wv[0],wv[1],wv[2],wv[3]);
  }
}

// ---------------------------------------------------------------------------
// ko: r18/r19 compute (proven 45us, 4 waves/SIMD); setprio on both MFMA
// clusters (r20, neutral-kept). BF16 partial epilogue + kred.
// ---------------------------------------------------------------------------
__global__ __launch_bounds__(512, 4) void ko(const ushort_t* __restrict__ kst,
                                             const ushort_t* __restrict__ qst,
                                             const ushort_t* __restrict__ vst,
                                             ushort_t* __restrict__ part,
                                             float* __restrict__ out){
  __shared__ __align__(16) char smem[65536];   // dbuf 2 x (Q 16K + V 16K)
  int wg = blockIdx.x;            // 512
  int kb  = wg & 63;              // 0..63 (128 k-rows); xcd = kb%8
  int qsp = wg >> 6;              // 0..7  (16 q-tiles of 64)
  int t = threadIdx.x, lane = t & 63, w = t >> 6;   // w in 0..7
  int kg = w & 3, qh = w >> 2;
  int r15 = lane & 15, g4 = lane >> 4;

  // kf[b][kk]: wave's 32 k-rows from global K stream (one-time, coalesced)
  short8 kf[2][4];
  { const char* kbp = (const char*)kst + (size_t)(kb*2 + (kg>>1))*16384;
    int rg0 = (kg & 1)*2;
    #pragma unroll
    for (int b=0;b<2;b++)
      #pragma unroll
      for (int kk=0;kk<4;kk++)
        kf[b][kk] = *(const short8*)(kbp + (((rg0+b)*4+kk)<<10) + lane*16);
  }
  // stage Q0/V0 into buf0
  { const char* qg = (const char*)qst + (size_t)(qsp*16)*16384;
    const char* vg = (const char*)vst + (size_t)(qsp*16)*16384;
    #pragma unroll
    for (int i=0;i<2;i++){
      gld16(qg + (t + i*512)*16, smem + (t + i*512)*16);
      gld16(vg + (t + i*512)*16, smem + 16384 + (t + i*512)*16);
    }
  }

  f32x4 zero = {0.f,0.f,0.f,0.f};
  f32x4 acc[2][8];
  #pragma unroll
  for (int b=0;b<2;b++)
    #pragma unroll
    for (int i=0;i<8;i++) acc[b][i] = zero;

  for (int it=0; it<16; ++it){
    __syncthreads();                 // buf(it) DMA drained; buf(it^1) free
    const char* Qb = smem + (it&1)*32768;
    const char* Vb = Qb + 16384;
    // prefetch next Q/V into other buffer (drained at next barrier)
    if (it+1 < 16){
      const char* qg = (const char*)qst + (size_t)(qsp*16+it+1)*16384;
      const char* vg = (const char*)vst + (size_t)(qsp*16+it+1)*16384;
      char* dst = smem + ((it+1)&1)*32768;
      #pragma unroll
      for (int i=0;i<2;i++){
        gld16(qg + (t + i*512)*16, dst + (t + i*512)*16);
        gld16(vg + (t + i*512)*16, dst + 16384 + (t + i*512)*16);
      }
    }
    // ---- G1: S^T for wave's 32 k-rows x its 32-q half ----
    unsigned pw[2][4];               // [b][word]
    #pragma unroll
    for (int blk=0; blk<2; ++blk){
      f32x4 s0 = zero, s1 = zero;
      __builtin_amdgcn_s_setprio(1);
      #pragma unroll
      for (int kk=0; kk<4; ++kk){
        short8 aq = *(const short8*)(Qb + (((qh*2+blk)*4+kk)<<10) + lane*16);
        s0 = __builtin_amdgcn_mfma_f32_16x16x32_bf16(aq, kf[0][kk], s0, 0, 0, 0);
        s1 = __builtin_amdgcn_mfma_f32_16x16x32_bf16(aq, kf[1][kk], s1, 0, 0, 0);
      }
      __builtin_amdgcn_s_setprio(0);
      #pragma unroll
      for (int b=0;b<2;b++){
        f32x4 s = b ? s1 : s0;
        float p0 = __builtin_exp2f(s[0]);
        float p1 = __builtin_exp2f(s[1]);
        float p2 = __builtin_exp2f(s[2]);
        float p3 = __builtin_exp2f(s[3]);
        unsigned wa, wb;
        asm("v_cvt_pk_bf16_f32 %0, %1, %2" : "=v"(wa) : "v"(p0), "v"(p1));
        asm("v_cvt_pk_bf16_f32 %0, %1, %2" : "=v"(wb) : "v"(p2), "v"(p3));
        pw[b][blk*2+0] = wa;
        pw[b][blk*2+1] = wb;
      }
    }
    short8 af[2];
    #pragma unroll
    for (int b=0;b<2;b++){
      asm("v_permlane32_swap_b32 %0, %1" : "+v"(pw[b][0]), "+v"(pw[b][2]));
      asm("v_permlane32_swap_b32 %0, %1" : "+v"(pw[b][1]), "+v"(pw[b][3]));
      asm("v_permlane16_swap_b32 %0, %1" : "+v"(pw[b][0]), "+v"(pw[b][2]));
      asm("v_permlane16_swap_b32 %0, %1" : "+v"(pw[b][1]), "+v"(pw[b][3]));
      uint4v fw = { pw[b][0], pw[b][1], pw[b][2], pw[b][3] };
      af[b] = __builtin_bit_cast(short8, fw);
    }
    // ---- PV: O += P~.V~ for wave's q-half ----
    __builtin_amdgcn_s_setprio(1);
    #pragma unroll
    for (int dvb=0; dvb<8; ++dvb){
      short8 bv = *(const short8*)(Vb + ((qh*8+dvb)<<10) + lane*16);
      acc[0][dvb] = __builtin_amdgcn_mfma_f32_16x16x32_bf16(af[0], bv, acc[0][dvb], 0, 0, 0);
      acc[1][dvb] = __builtin_amdgcn_mfma_f32_16x16x32_bf16(af[1], bv, acc[1][dvb], 0, 0, 0);
    }
    __builtin_amdgcn_s_setprio(0);
  }
  // ---- epilogue: qh-pair reduce via LDS (one 64KB pass, deterministic),
  //      then qh=0 stores BF16 partials into slice [qsp] (or atomic) ----
  __syncthreads();                   // all waves done with buffers
  f32x4* red = (f32x4*)smem;         // [b*8+dvb][kg*64+lane]
  if (qh == 1){
    #pragma unroll
    for (int b=0;b<2;b++)
      #pragma unroll
      for (int dvb=0; dvb<8; ++dvb)
        red[((b*8 + dvb)<<8) + kg*64 + lane] = acc[b][dvb];
  }
  __syncthreads();
  if (qh == 0){
    ushort_t* ps = part ? (part + (size_t)qsp*SK*DD) : (ushort_t*)0;
    #pragma unroll
    for (int b=0;b<2;b++)
      #pragma unroll
      for (int dvb=0; dvb<8; ++dvb){
        f32x4 o = red[((b*8 + dvb)<<8) + kg*64 + lane];
        f32x4 a = acc[b][dvb];
        #pragma unroll
        for (int j=0;j<4;j++){
          int k  = kb*128 + kg*32 + b*16 + g4*4 + j;
          int dv = dvb*16 + r15;
          if (ps) ps[(size_t)k*DD + dv] = f2bf(a[j] + o[j]);
          else    atomicAdd(out + (size_t)k*DD + dv, a[j] + o[j]);
        }
      }
  }
}

// ---------------------------------------------------------------------------
// kred: out = sum of 8 BF16 partial slices, fixed order (deterministic).
// ---------------------------------------------------------------------------
__global__ __launch_bounds__(256) void kred(const ushort_t* __restrict__ part,
                                            float* __restrict__ out){
  int i = blockIdx.x*256 + threadIdx.x;          // 0..131071
  const uint4* p = (const uint4*)part;           // 8 bf16 per uint4
  float a0=0,a1=0,a2=0,a3=0,a4=0,a5=0,a6=0,a7=0;
  #pragma unroll
  for (int s=0;s<8;s++){
    uint4 v = p[(size_t)s*131072 + i];
    a0 += __uint_as_float((v.x & 0xFFFFu) << 16);
    a1 += __uint_as_float(v.x & 0xFFFF0000u);
    a2 += __uint_as_float((v.y & 0xFFFFu) << 16);
    a3 += __uint_as_float(v.y & 0xFFFF0000u);
    a4 += __uint_as_float((v.z & 0xFFFFu) << 16);
    a5 += __uint_as_float(v.z & 0xFFFF0000u);
    a6 += __uint_as_float((v.w & 0xFFFFu) << 16);
    a7 += __uint_as_float(v.w & 0xFFFF0000u);
  }
  float4* o4 = (float4*)out;
  o4[(size_t)i*2 + 0] = make_float4(a0,a1,a2,a3);
  o4[(size_t)i*2 + 1] = make_float4(a4,a5,a6,a7);
}

extern "C" void kernel_launch(void* const* d_in, const int* in_sizes, int n_in,
                              void* d_out, int out_size, void* d_ws, size_t ws_size,
                              hipStream_t stream) {
  const float* Kp = (const float*)d_in[0];
  const float* Qp = (const float*)d_in[1];
  const float* Vp = (const float*)d_in[2];
  float* out = (float*)d_out;
  char* ws = (char*)d_ws;
  ushort_t* kst  = (ushort_t*)ws;
  ushort_t* qst  = (ushort_t*)(ws + ((size_t)2<<20));
  ushort_t* vst  = (ushort_t*)(ws + ((size_t)4<<20));
  float* zpart   = (float*)(ws + ((size_t)6<<20));   // 16 x 32KB = 512KB
  // partials: 8 bf16 slices x 2MB at ws+8MB (16MB; gate kept at 40MB)
  bool use_part = ws_size >= ((size_t)40<<20);
  ushort_t* part = use_part ? (ushort_t*)(ws + ((size_t)8<<20)) : (ushort_t*)0;

  prep_kq<<<dim3(1024), dim3(256), 0, stream>>>(Kp, Qp, kst, qst);
  kz     <<<dim3(1024), dim3(256), 0, stream>>>(kst, qst, zpart);
  prep_v <<<dim3(256),  dim3(256), 0, stream>>>(Vp, zpart, vst);
  if (use_part){
    ko   <<<dim3(512),  dim3(512), 0, stream>>>(kst, qst, vst, part, out);
    kred <<<dim3(512),  dim3(256), 0, stream>>>(part, out);
  } else {
    hipMemsetAsync(d_out, 0, (size_t)SK*DD*sizeof(float), stream);
    ko   <<<dim3(512),  dim3(512), 0, stream>>>(kst, qst, vst, (ushort_t*)0, out);
  }
}

// Round 22
// 78.777 us; speedup vs baseline: 1.7808x; 1.7808x over previous
//
#include <hip/hip_runtime.h>

#define SK 8192
#define SQ 8192
#define DD 128
#define ZSPLIT 8

typedef __attribute__((ext_vector_type(8))) short short8;
typedef __attribute__((ext_vector_type(4))) float f32x4;
typedef __attribute__((ext_vector_type(4))) unsigned uint4v;
typedef unsigned short ushort_t;

// round-to-nearest-even f32 -> bf16
__device__ __forceinline__ unsigned short f2bf(float x){
  unsigned int u = __float_as_uint(x);
  u += 0x7FFFu + ((u >> 16) & 1u);
  return (unsigned short)(u >> 16);
}

// async global->LDS DMA, 16B/lane. LDS dest = uniform base + lane*16.
__device__ __forceinline__ void gld16(const void* g, void* l){
  __builtin_amdgcn_global_load_lds(
      (const __attribute__((address_space(1))) unsigned int*)g,
      (__attribute__((address_space(3))) unsigned int*)l, 16, 0, 0);
}

// ---------------------------------------------------------------------------
// STREAM LAYOUTS (fragment-record form; all reads are coalesced 1KB records)
// K/Q stream: per 64-row tile, 16 records of 1KB; rec = rg*4 + kk.
//   Lane l, byte pair j: element M[tile*64 + rg*16 + (l&15)][kk*32 + (l>>4)*8 + j]
// V stream: per 64-q tile, 16 records; rec = qc*8 + dvb. Lane l:
//   element V^T[dvb*16 + (l&15)][qc*32 + (l>>4)*8 + j]  (V^T pre-scaled 1/Z)
// ---------------------------------------------------------------------------

// prep_kq: cast K (pre-scaled by log2(e)/sqrt(128)) and Q to bf16 streams.
__global__ __launch_bounds__(256) void prep_kq(const float* __restrict__ Kp,
                                               const float* __restrict__ Qp,
                                               ushort_t* __restrict__ kst,
                                               ushort_t* __restrict__ qst){
  int g = blockIdx.x*256 + threadIdx.x;
  int arr = g >> 17;
  int s   = g & 131071;
  int row = s >> 4;
  int c16 = s & 15;            // 8-elem slot: d = c16*8..c16*8+7
  const float* src = (arr ? Qp : Kp) + row*DD + c16*8;
  const float scale = arr ? 1.0f : 0.12751743f;   // log2(e)/sqrt(128)
  float4 f0 = ((const float4*)src)[0];
  float4 f1 = ((const float4*)src)[1];
  unsigned int wv[4];
  wv[0] = (unsigned)f2bf(f0.x*scale) | ((unsigned)f2bf(f0.y*scale) << 16);
  wv[1] = (unsigned)f2bf(f0.z*scale) | ((unsigned)f2bf(f0.w*scale) << 16);
  wv[2] = (unsigned)f2bf(f1.x*scale) | ((unsigned)f2bf(f1.y*scale) << 16);
  wv[3] = (unsigned)f2bf(f1.z*scale) | ((unsigned)f2bf(f1.w*scale) << 16);
  ushort_t* base = arr ? qst : kst;
  int tile = row >> 6, rg = (row >> 4) & 3, r15 = row & 15;
  int kk = c16 >> 2, g4 = c16 & 3;
  char* dst = (char*)base + (size_t)tile*16384 + (rg*4 + kk)*1024 + (g4*16 + r15)*16;
  ((uint4*)dst)[0] = make_uint4(wv[0],wv[1],wv[2],wv[3]);
}

// ---------------------------------------------------------------------------
// kz: per-column stats, BARRIER-FREE main loop + 1-deep register prefetch
// of the next K records (r17/r19 — passing). wgid = qs*8 + kspl keeps all
// 128 q-stripe WGs of one kspl on one XCD -> K slice L2-resident (r21's
// remap broke this and went HBM-bound; reverted).
// ---------------------------------------------------------------------------
__global__ __launch_bounds__(256, 4) void kz(const ushort_t* __restrict__ kst,
                                             const ushort_t* __restrict__ qst,
                                             float* __restrict__ zpart){
  __shared__ __align__(16) float zred[256];
  int wg = blockIdx.x;            // 1024
  int qs   = wg >> 3;             // 0..127 (64-q stripe)
  int kspl = wg & 7;
  int t = threadIdx.x, lane = t & 63, w = t >> 6;   // w in 0..3

  short8 qf[4][4];
  { const char* qg = (const char*)qst + (size_t)qs*16384;
    #pragma unroll
    for (int qg_=0; qg_<4; ++qg_)
      #pragma unroll
      for (int kk=0; kk<4; ++kk)
        qf[qg_][kk] = *(const short8*)(qg + ((qg_*4+kk)<<10) + lane*16);
  }

  float zac0=0.f, zac1=0.f, zac2=0.f, zac3=0.f;
  const char* kbase = (const char*)kst + (size_t)(kspl*16)*16384 + ((w*4)<<10) + lane*16;
  short8 ak[4];
  #pragma unroll
  for (int kk=0;kk<4;kk++)
    ak[kk] = *(const short8*)(kbase + (kk<<10));
  for (int it=0; it<16; ++it){
    int nit = (it+1 < 16) ? it+1 : 15;
    short8 nk[4];
    #pragma unroll
    for (int kk=0;kk<4;kk++)
      nk[kk] = *(const short8*)(kbase + (size_t)nit*16384 + (kk<<10));
    f32x4 s0={0,0,0,0}, s1={0,0,0,0}, s2={0,0,0,0}, s3={0,0,0,0};
    #pragma unroll
    for (int kk=0; kk<4; ++kk){
      s0 = __builtin_amdgcn_mfma_f32_16x16x32_bf16(ak[kk], qf[0][kk], s0, 0, 0, 0);
      s1 = __builtin_amdgcn_mfma_f32_16x16x32_bf16(ak[kk], qf[1][kk], s1, 0, 0, 0);
      s2 = __builtin_amdgcn_mfma_f32_16x16x32_bf16(ak[kk], qf[2][kk], s2, 0, 0, 0);
      s3 = __builtin_amdgcn_mfma_f32_16x16x32_bf16(ak[kk], qf[3][kk], s3, 0, 0, 0);
    }
    #pragma unroll
    for (int j=0;j<4;j++){
      zac0 += __builtin_exp2f(s0[j]);
      zac1 += __builtin_exp2f(s1[j]);
      zac2 += __builtin_exp2f(s2[j]);
      zac3 += __builtin_exp2f(s3[j]);
    }
    #pragma unroll
    for (int kk=0;kk<4;kk++) ak[kk] = nk[kk];
  }
  zac0 += __shfl_xor(zac0,16); zac0 += __shfl_xor(zac0,32);
  zac1 += __shfl_xor(zac1,16); zac1 += __shfl_xor(zac1,32);
  zac2 += __shfl_xor(zac2,16); zac2 += __shfl_xor(zac2,32);
  zac3 += __shfl_xor(zac3,16); zac3 += __shfl_xor(zac3,32);
  if (lane < 16){
    zred[w*64 + 0*16 + lane] = zac0;
    zred[w*64 + 1*16 + lane] = zac1;
    zred[w*64 + 2*16 + lane] = zac2;
    zred[w*64 + 3*16 + lane] = zac3;
  }
  __syncthreads();
  if (t < 64){
    float z = zred[t] + zred[64+t] + zred[128+t] + zred[192+t];
    zpart[(size_t)kspl*SQ + qs*64 + t] = z;
  }
}

// ---------------------------------------------------------------------------
// prep_v: runs AFTER kz. Vt[q,:] = V[q,:] / Z_q -> V stream records.
// Grid 256 = 128 tiles x 2 q-halves (r20 — passing).
// ---------------------------------------------------------------------------
__global__ __launch_bounds__(256) void prep_v(const float* __restrict__ Vp,
                                              const float* __restrict__ zpart,
                                              ushort_t* __restrict__ vst){
  __shared__ ushort_t vl[32][132];
  int tile = blockIdx.x >> 1;     // 0..127
  int qc   = blockIdx.x & 1;      // q-half
  int t = threadIdx.x;
  int qr = t >> 3;                // 0..31 local q row
  int dvb16 = (t & 7)*16;         // dv chunk of 16
  int q = tile*64 + qc*32 + qr;
  float z = 0.f;
  #pragma unroll
  for (int s=0;s<ZSPLIT;s++) z += zpart[(size_t)s*SQ + q];
  float vinv = 1.0f / z;
  const float* src = Vp + (size_t)q*DD + dvb16;
  #pragma unroll
  for (int j=0;j<4;j++){
    float4 f = ((const float4*)src)[j];
    vl[qr][dvb16 + j*4 + 0] = f2bf(f.x*vinv);
    vl[qr][dvb16 + j*4 + 1] = f2bf(f.y*vinv);
    vl[qr][dvb16 + j*4 + 2] = f2bf(f.z*vinv);
    vl[qr][dvb16 + j*4 + 3] = f2bf(f.w*vinv);
  }
  __syncthreads();
  char* obase = (char*)vst + (size_t)tile*16384;
  #pragma unroll
  for (int s2=0;s2<2;s2++){
    int sid = t*2 + s2;                 // 0..511 = rec_local*64 + lane
    int recl = sid >> 6, lr = sid & 63;
    int dv = recl*16 + (lr & 15);       // recl = dvb (0..7)
    int qb = (lr >> 4)*8;               // local q base within half
    unsigned int wv[4];
    #pragma unroll
    for (int p=0;p<4;p++){
      unsigned lo = vl[qb + p*2 + 0][dv];
      unsigned hi = vl[qb + p*2 + 1][dv];
      wv[p] = lo | (hi << 16);
    }
    ((uint4*)(obase + (qc*8 + recl)*1024 + lr*16))[0] = make_uint4(wv[0],wv[1],wv[2],wv[3]);
  }
}

// ---------------------------------------------------------------------------
// ko: r18/r19 compute (proven 45us, 4 waves/SIMD); setprio on both MFMA
// clusters (r20, neutral-kept). BF16 partial epilogue + kred.
// ---------------------------------------------------------------------------
__global__ __launch_bounds__(512, 4) void ko(const ushort_t* __restrict__ kst,
                                             const ushort_t* __restrict__ qst,
                                             const ushort_t* __restrict__ vst,
                                             ushort_t* __restrict__ part,
                                             float* __restrict__ out){
  __shared__ __align__(16) char smem[65536];   // dbuf 2 x (Q 16K + V 16K)
  int wg = blockIdx.x;            // 512
  int kb  = wg & 63;              // 0..63 (128 k-rows); xcd = kb%8
  int qsp = wg >> 6;              // 0..7  (16 q-tiles of 64)
  int t = threadIdx.x, lane = t & 63, w = t >> 6;   // w in 0..7
  int kg = w & 3, qh = w >> 2;
  int r15 = lane & 15, g4 = lane >> 4;

  // kf[b][kk]: wave's 32 k-rows from global K stream (one-time, coalesced)
  short8 kf[2][4];
  { const char* kbp = (const char*)kst + (size_t)(kb*2 + (kg>>1))*16384;
    int rg0 = (kg & 1)*2;
    #pragma unroll
    for (int b=0;b<2;b++)
      #pragma unroll
      for (int kk=0;kk<4;kk++)
        kf[b][kk] = *(const short8*)(kbp + (((rg0+b)*4+kk)<<10) + lane*16);
  }
  // stage Q0/V0 into buf0
  { const char* qg = (const char*)qst + (size_t)(qsp*16)*16384;
    const char* vg = (const char*)vst + (size_t)(qsp*16)*16384;
    #pragma unroll
    for (int i=0;i<2;i++){
      gld16(qg + (t + i*512)*16, smem + (t + i*512)*16);
      gld16(vg + (t + i*512)*16, smem + 16384 + (t + i*512)*16);
    }
  }

  f32x4 zero = {0.f,0.f,0.f,0.f};
  f32x4 acc[2][8];
  #pragma unroll
  for (int b=0;b<2;b++)
    #pragma unroll
    for (int i=0;i<8;i++) acc[b][i] = zero;

  for (int it=0; it<16; ++it){
    __syncthreads();                 // buf(it) DMA drained; buf(it^1) free
    const char* Qb = smem + (it&1)*32768;
    const char* Vb = Qb + 16384;
    // prefetch next Q/V into other buffer (drained at next barrier)
    if (it+1 < 16){
      const char* qg = (const char*)qst + (size_t)(qsp*16+it+1)*16384;
      const char* vg = (const char*)vst + (size_t)(qsp*16+it+1)*16384;
      char* dst = smem + ((it+1)&1)*32768;
      #pragma unroll
      for (int i=0;i<2;i++){
        gld16(qg + (t + i*512)*16, dst + (t + i*512)*16);
        gld16(vg + (t + i*512)*16, dst + 16384 + (t + i*512)*16);
      }
    }
    // ---- G1: S^T for wave's 32 k-rows x its 32-q half ----
    unsigned pw[2][4];               // [b][word]
    #pragma unroll
    for (int blk=0; blk<2; ++blk){
      f32x4 s0 = zero, s1 = zero;
      __builtin_amdgcn_s_setprio(1);
      #pragma unroll
      for (int kk=0; kk<4; ++kk){
        short8 aq = *(const short8*)(Qb + (((qh*2+blk)*4+kk)<<10) + lane*16);
        s0 = __builtin_amdgcn_mfma_f32_16x16x32_bf16(aq, kf[0][kk], s0, 0, 0, 0);
        s1 = __builtin_amdgcn_mfma_f32_16x16x32_bf16(aq, kf[1][kk], s1, 0, 0, 0);
      }
      __builtin_amdgcn_s_setprio(0);
      #pragma unroll
      for (int b=0;b<2;b++){
        f32x4 s = b ? s1 : s0;
        float p0 = __builtin_exp2f(s[0]);
        float p1 = __builtin_exp2f(s[1]);
        float p2 = __builtin_exp2f(s[2]);
        float p3 = __builtin_exp2f(s[3]);
        unsigned wa, wb;
        asm("v_cvt_pk_bf16_f32 %0, %1, %2" : "=v"(wa) : "v"(p0), "v"(p1));
        asm("v_cvt_pk_bf16_f32 %0, %1, %2" : "=v"(wb) : "v"(p2), "v"(p3));
        pw[b][blk*2+0] = wa;
        pw[b][blk*2+1] = wb;
      }
    }
    short8 af[2];
    #pragma unroll
    for (int b=0;b<2;b++){
      asm("v_permlane32_swap_b32 %0, %1" : "+v"(pw[b][0]), "+v"(pw[b][2]));
      asm("v_permlane32_swap_b32 %0, %1" : "+v"(pw[b][1]), "+v"(pw[b][3]));
      asm("v_permlane16_swap_b32 %0, %1" : "+v"(pw[b][0]), "+v"(pw[b][2]));
      asm("v_permlane16_swap_b32 %0, %1" : "+v"(pw[b][1]), "+v"(pw[b][3]));
      uint4v fw = { pw[b][0], pw[b][1], pw[b][2], pw[b][3] };
      af[b] = __builtin_bit_cast(short8, fw);
    }
    // ---- PV: O += P~.V~ for wave's q-half ----
    __builtin_amdgcn_s_setprio(1);
    #pragma unroll
    for (int dvb=0; dvb<8; ++dvb){
      short8 bv = *(const short8*)(Vb + ((qh*8+dvb)<<10) + lane*16);
      acc[0][dvb] = __builtin_amdgcn_mfma_f32_16x16x32_bf16(af[0], bv, acc[0][dvb], 0, 0, 0);
      acc[1][dvb] = __builtin_amdgcn_mfma_f32_16x16x32_bf16(af[1], bv, acc[1][dvb], 0, 0, 0);
    }
    __builtin_amdgcn_s_setprio(0);
  }
  // ---- epilogue: qh-pair reduce via LDS (one 64KB pass, deterministic),
  //      then qh=0 stores BF16 partials into slice [qsp] (or atomic) ----
  __syncthreads();                   // all waves done with buffers
  f32x4* red = (f32x4*)smem;         // [b*8+dvb][kg*64+lane]
  if (qh == 1){
    #pragma unroll
    for (int b=0;b<2;b++)
      #pragma unroll
      for (int dvb=0; dvb<8; ++dvb)
        red[((b*8 + dvb)<<8) + kg*64 + lane] = acc[b][dvb];
  }
  __syncthreads();
  if (qh == 0){
    ushort_t* ps = part ? (part + (size_t)qsp*SK*DD) : (ushort_t*)0;
    #pragma unroll
    for (int b=0;b<2;b++)
      #pragma unroll
      for (int dvb=0; dvb<8; ++dvb){
        f32x4 o = red[((b*8 + dvb)<<8) + kg*64 + lane];
        f32x4 a = acc[b][dvb];
        #pragma unroll
        for (int j=0;j<4;j++){
          int k  = kb*128 + kg*32 + b*16 + g4*4 + j;
          int dv = dvb*16 + r15;
          if (ps) ps[(size_t)k*DD + dv] = f2bf(a[j] + o[j]);
          else    atomicAdd(out + (size_t)k*DD + dv, a[j] + o[j]);
        }
      }
  }
}

// ---------------------------------------------------------------------------
// kred: out = sum of 8 BF16 partial slices, fixed order (deterministic).
// ---------------------------------------------------------------------------
__global__ __launch_bounds__(256) void kred(const ushort_t* __restrict__ part,
                                            float* __restrict__ out){
  int i = blockIdx.x*256 + threadIdx.x;          // 0..131071
  const uint4* p = (const uint4*)part;           // 8 bf16 per uint4
  float a0=0,a1=0,a2=0,a3=0,a4=0,a5=0,a6=0,a7=0;
  #pragma unroll
  for (int s=0;s<8;s++){
    uint4 v = p[(size_t)s*131072 + i];
    a0 += __uint_as_float((v.x & 0xFFFFu) << 16);
    a1 += __uint_as_float(v.x & 0xFFFF0000u);
    a2 += __uint_as_float((v.y & 0xFFFFu) << 16);
    a3 += __uint_as_float(v.y & 0xFFFF0000u);
    a4 += __uint_as_float((v.z & 0xFFFFu) << 16);
    a5 += __uint_as_float(v.z & 0xFFFF0000u);
    a6 += __uint_as_float((v.w & 0xFFFFu) << 16);
    a7 += __uint_as_float(v.w & 0xFFFF0000u);
  }
  float4* o4 = (float4*)out;
  o4[(size_t)i*2 + 0] = make_float4(a0,a1,a2,a3);
  o4[(size_t)i*2 + 1] = make_float4(a4,a5,a6,a7);
}

extern "C" void kernel_launch(void* const* d_in, const int* in_sizes, int n_in,
                              void* d_out, int out_size, void* d_ws, size_t ws_size,
                              hipStream_t stream) {
  const float* Kp = (const float*)d_in[0];
  const float* Qp = (const float*)d_in[1];
  const float* Vp = (const float*)d_in[2];
  float* out = (float*)d_out;
  char* ws = (char*)d_ws;
  ushort_t* kst  = (ushort_t*)ws;
  ushort_t* qst  = (ushort_t*)(ws + ((size_t)2<<20));
  ushort_t* vst  = (ushort_t*)(ws + ((size_t)4<<20));
  float* zpart   = (float*)(ws + ((size_t)6<<20));
  // partials: 8 bf16 slices x 2MB at ws+8MB (16MB; gate kept at 40MB)
  bool use_part = ws_size >= ((size_t)40<<20);
  ushort_t* part = use_part ? (ushort_t*)(ws + ((size_t)8<<20)) : (ushort_t*)0;

  prep_kq<<<dim3(1024), dim3(256), 0, stream>>>(Kp, Qp, kst, qst);
  kz     <<<dim3(1024), dim3(256), 0, stream>>>(kst, qst, zpart);
  prep_v <<<dim3(256),  dim3(256), 0, stream>>>(Vp, zpart, vst);
  if (use_part){
    ko   <<<dim3(512),  dim3(512), 0, stream>>>(kst, qst, vst, part, out);
    kred <<<dim3(512),  dim3(256), 0, stream>>>(part, out);
  } else {
    hipMemsetAsync(d_out, 0, (size_t)SK*DD*sizeof(float), stream);
    ko   <<<dim3(512),  dim3(512), 0, stream>>>(kst, qst, vst, (ushort_t*)0, out);
  }
}